// Round 6
// baseline (412.561 us; speedup 1.0000x reference)
//
#include <hip/hip_runtime.h>
#include <stdint.h>

typedef __bf16 bf16_t;
typedef __bf16 bf16x8 __attribute__((ext_vector_type(8)));
typedef float f32x4 __attribute__((ext_vector_type(4)));
typedef uint32_t u32x4 __attribute__((ext_vector_type(4)));

#define N_NODES  50000
#define N_EDGES  400000
#define D_IN     512
#define D_HID    512
#define D_OUTD   256
#define M_PAD    50048   // 391 * 128 (GEMM M padded; pad rows zeroed)
#define NB_SCAN  196     // ceil(50000/256)

// ---------- helpers ----------
__device__ __forceinline__ uint32_t f2bf_bits(float x){
    uint32_t u = __float_as_uint(x);
    return (u + 0x7fffu + ((u >> 16) & 1u)) >> 16;   // RNE
}
__device__ __forceinline__ void unpack8(uint4 v, float* f){
    f[0]=__uint_as_float(v.x<<16); f[1]=__uint_as_float(v.x & 0xffff0000u);
    f[2]=__uint_as_float(v.y<<16); f[3]=__uint_as_float(v.y & 0xffff0000u);
    f[4]=__uint_as_float(v.z<<16); f[5]=__uint_as_float(v.z & 0xffff0000u);
    f[6]=__uint_as_float(v.w<<16); f[7]=__uint_as_float(v.w & 0xffff0000u);
}
__device__ __forceinline__ void glds16(const bf16_t* g, bf16_t* l){
    __builtin_amdgcn_global_load_lds(
        (const __attribute__((address_space(1))) uint32_t*)g,
        (__attribute__((address_space(3))) uint32_t*)l, 16, 0, 0);
}

// ---------- dtype conversion (+ deg init + counter zero folded in) ----------
__global__ __launch_bounds__(256)
void conv_x_bf16(const float* __restrict__ x, bf16_t* __restrict__ Xb,
                 int* __restrict__ deg, int* __restrict__ cnt){
    const int t = blockIdx.x * 256 + threadIdx.x;   // 4 elements per thread
    if (t == 0) *cnt = 0;                            // edge-slot counter for k_reserve
    if (t < N_NODES) deg[t] = 1;                    // self-loop degree init
    const int row = t >> 7;                          // (4t)/512
    uint2 o;
    if (row < N_NODES){
        f32x4 v = __builtin_nontemporal_load(((const f32x4*)x) + t);
        o.x = f2bf_bits(v.x) | (f2bf_bits(v.y) << 16);
        o.y = f2bf_bits(v.z) | (f2bf_bits(v.w) << 16);
    } else { o.x = 0u; o.y = 0u; }                   // zero pad rows
    ((uint2*)Xb)[t] = o;
}

// Both weight transposes + edge degree count in one launch.
// grid = 1568 blocks (401408 threads >= max(768*512, N_EDGES))
__global__ __launch_bounds__(256)
void conv_w_both(const float* __restrict__ W1, const float* __restrict__ W2,
                 bf16_t* __restrict__ W1t, bf16_t* __restrict__ W2t,
                 const int* __restrict__ ei, int* __restrict__ deg){
    const int idx = blockIdx.x * 256 + threadIdx.x;  // n*512 + k
    if (idx < N_EDGES) atomicAdd(&deg[ei[N_EDGES + idx]], 1);
    const int n = idx >> 9;
    const int k = idx & 511;
    if (n < 512) W1t[idx] = (bf16_t)W1[k * 512 + n];
    else if (n < 768) W2t[(n - 512) * 512 + k] = (bf16_t)W2[k * 256 + (n - 512)];
}

// ---------- CSR build: single-kernel atomic range reservation ----------
// rowp need NOT be monotonic in node id -- each node just needs a private,
// disjoint slot range [rowp[i], rowe[i]) for its inbound edges. Reserve via
// atomicAdd (LLVM atomic-optimizer turns this into one wave-level add).
// Replaces the 3-kernel scan chain.
__global__ __launch_bounds__(256)
void k_reserve(const int* __restrict__ deg, float* __restrict__ dinv,
               int* __restrict__ rowp, int* __restrict__ rowe,
               int* __restrict__ cursor, int* __restrict__ cnt){
    int i = blockIdx.x*256 + threadIdx.x;
    if (i < N_NODES){
        int d = deg[i];
        dinv[i] = rsqrtf((float)d);
        int r = atomicAdd(cnt, d - 1);
        rowp[i]   = r;
        rowe[i]   = r + d - 1;
        cursor[i] = r;
    }
}
__global__ __launch_bounds__(256)
void k_place(const int* __restrict__ ei, const float* __restrict__ dinv,
             int* __restrict__ cursor, int* __restrict__ csrc, float* __restrict__ cnorm){
    int e = blockIdx.x*256 + threadIdx.x;
    if (e < N_EDGES){
        int s = ei[e];
        int d = ei[N_EDGES + e];
        int p = atomicAdd(&cursor[d], 1);
        csrc[p]  = s;
        cnorm[p] = dinv[s] * dinv[d];
    }
}

// ---------- bf16 MFMA GEMM: C[M_PAD][N] = A[M_PAD][K] @ Bt[N][K]^T ----------
// 128x128 tile, BK=64, 256 threads = 4 waves in 2x2, each wave 64x64 (4x4 MFMA 16x16x32).
// T3+T4: double-buffered LDS, RAW s_barrier + counted `s_waitcnt vmcnt(8)` so the
// next tile's 8 global_load_lds stay in flight across this tile's compute.
// T2: XOR swizzle (elem ^= (row&7)<<3) applied to pre-swizzled global SOURCE
// (LDS dest stays linear for global_load_lds) and to the ds_read address.
__global__ __launch_bounds__(256, 2)
void gemm_bf16_mfma(const bf16_t* __restrict__ A, const bf16_t* __restrict__ Bt,
                    bf16_t* __restrict__ C, int N, int K)
{
    __shared__ bf16_t As[2][128*64];   // 2 x 16 KB
    __shared__ bf16_t Bs[2][128*64];   // 2 x 16 KB

    const int tid  = threadIdx.x;
    const int wave = tid >> 6;
    const int lane = tid & 63;
    const int wr = wave >> 1;
    const int wc = wave & 1;
    const int mBase = blockIdx.x * 128;
    const int nBase = blockIdx.y * 128;

    // ---- staging map: round r (0..3), thread t -> linear LDS slot (r*256+t)*8 elems
    // row = r*32 + wave*8 + (lane>>3); 16B-chunk = (lane&7) ^ (lane>>3)  [pre-swizzled src]
    const int sr = lane >> 3;                 // == row & 7
    const int sc = (lane & 7) ^ sr;           // swizzled chunk index
    const bf16_t* Asrc[4]; const bf16_t* Bsrc[4];
    #pragma unroll
    for (int r = 0; r < 4; ++r){
        const int row = r*32 + wave*8 + sr;
        Asrc[r] = A  + (size_t)(mBase + row) * K + sc*8;
        Bsrc[r] = Bt + (size_t)(nBase + row) * K + sc*8;
    }

    auto stage = [&](int k0, int p){
        bf16_t* Ad = &As[p][0];
        bf16_t* Bd = &Bs[p][0];
        #pragma unroll
        for (int r = 0; r < 4; ++r) glds16(Asrc[r] + k0, Ad + (r*256 + tid)*8);
        #pragma unroll
        for (int r = 0; r < 4; ++r) glds16(Bsrc[r] + k0, Bd + (r*256 + tid)*8);
    };

    // ---- fragment addressing: A[m=lane&15][k=kk*32+q*8+j], read addr XOR-swizzled
    const int m16 = lane & 15;
    const int q8  = (lane >> 4) << 3;         // q*8
    const int swz = (m16 & 7) << 3;           // elem-index XOR within a 64-elem row
    const int aBase = (wr*64 + m16)*64;
    const int bBase = (wc*64 + m16)*64;

    f32x4 acc[4][4] = {};

    stage(0, 0);                               // prologue: tile 0 -> buf 0
    const int KT = K >> 6;
    for (int kt = 0; kt < KT; ++kt){
        const int p = kt & 1;
        __builtin_amdgcn_s_barrier();          // B1: all waves done reading buf p^1
        __builtin_amdgcn_sched_barrier(0);
        if (kt + 1 < KT){
            stage((kt + 1) << 6, p ^ 1);       // 8 loads in flight across compute
            asm volatile("s_waitcnt vmcnt(8)" ::: "memory");   // tile kt's 8 oldest done
        } else {
            asm volatile("s_waitcnt vmcnt(0)" ::: "memory");
        }
        __builtin_amdgcn_sched_barrier(0);
        __builtin_amdgcn_s_barrier();          // B2: every wave's tile-kt loads landed
        const bf16_t* Ab = &As[p][0];
        const bf16_t* Bb = &Bs[p][0];
        #pragma unroll
        for (int kk = 0; kk < 2; ++kk){
            const int ko = (kk*32 + q8) ^ swz;
            bf16x8 a[4], b[4];
            #pragma unroll
            for (int t = 0; t < 4; ++t){
                a[t] = *(const bf16x8*)(Ab + aBase + t*1024 + ko);
                b[t] = *(const bf16x8*)(Bb + bBase + t*1024 + ko);
            }
            #pragma unroll
            for (int i = 0; i < 4; ++i){
                #pragma unroll
                for (int j = 0; j < 4; ++j){
                    acc[i][j] = __builtin_amdgcn_mfma_f32_16x16x32_bf16(a[i], b[j], acc[i][j], 0, 0, 0);
                }
            }
        }
    }

    // C/D layout: col = lane&15, row = q*4 + reg  [measured mapping]
    const int qr = lane >> 4;
    #pragma unroll
    for (int i = 0; i < 4; ++i){
        const int row0 = mBase + wr*64 + i*16 + qr*4;
        #pragma unroll
        for (int j = 0; j < 4; ++j){
            const int col = nBase + wc*64 + j*16 + m16;
            bf16_t* Cp = C + (size_t)row0 * N + col;
            #pragma unroll
            for (int r = 0; r < 4; ++r)
                Cp[(size_t)r * N] = (bf16_t)acc[i][j][r];
        }
    }
}

// ---------- aggregation ----------
// layer 1: H[i] = relu(sum_e norm*T[src] + dinv[i]^2*T[i] + b), D=512, bf16 out
// one wave per node; edge loop unrolled x4 (4 row-gathers in flight; measured best).
// Launched TWICE over node ranges (nodeBase param) so each dispatch is ~35 us --
// makes the profile's top-5 surface whichever OTHER dispatch is truly longest.
__global__ __launch_bounds__(256)
void agg_bias_relu_512(const bf16_t* __restrict__ T, const int* __restrict__ rowp,
                       const int* __restrict__ rowe,
                       const int* __restrict__ csrc, const float* __restrict__ cnorm,
                       const float* __restrict__ dinv, const float* __restrict__ bias,
                       bf16_t* __restrict__ H, int nodeBase)
{
    const int gw   = nodeBase + ((blockIdx.x * 256 + threadIdx.x) >> 6);
    const int lane = threadIdx.x & 63;
    if (gw >= N_NODES) return;
    const float di = dinv[gw];
    float acc[8];
    {
        uint4 v = ((const uint4*)(T + (size_t)gw * 512))[lane];
        float f[8]; unpack8(v, f);
        const float w = di * di;
        #pragma unroll
        for (int j = 0; j < 8; ++j) acc[j] = w * f[j];
    }
    int e = rowp[gw];
    const int e1 = rowe[gw];
    for (; e + 4 <= e1; e += 4){
        const int   s0 = csrc[e],   s1 = csrc[e+1], s2 = csrc[e+2], s3 = csrc[e+3];
        const float w0 = cnorm[e],  w1 = cnorm[e+1], w2 = cnorm[e+2], w3 = cnorm[e+3];
        uint4 v0 = ((const uint4*)(T + (size_t)s0 * 512))[lane];
        uint4 v1 = ((const uint4*)(T + (size_t)s1 * 512))[lane];
        uint4 v2 = ((const uint4*)(T + (size_t)s2 * 512))[lane];
        uint4 v3 = ((const uint4*)(T + (size_t)s3 * 512))[lane];
        float f[8];
        unpack8(v0, f);
        #pragma unroll
        for (int j = 0; j < 8; ++j) acc[j] += w0 * f[j];
        unpack8(v1, f);
        #pragma unroll
        for (int j = 0; j < 8; ++j) acc[j] += w1 * f[j];
        unpack8(v2, f);
        #pragma unroll
        for (int j = 0; j < 8; ++j) acc[j] += w2 * f[j];
        unpack8(v3, f);
        #pragma unroll
        for (int j = 0; j < 8; ++j) acc[j] += w3 * f[j];
    }
    for (; e < e1; ++e){
        const int   s = csrc[e];
        const float w = cnorm[e];
        uint4 v = ((const uint4*)(T + (size_t)s * 512))[lane];
        float f[8]; unpack8(v, f);
        #pragma unroll
        for (int j = 0; j < 8; ++j) acc[j] += w * f[j];
    }
    const float4 b0 = ((const float4*)bias)[lane*2];
    const float4 b1 = ((const float4*)bias)[lane*2 + 1];
    float r[8] = {acc[0]+b0.x, acc[1]+b0.y, acc[2]+b0.z, acc[3]+b0.w,
                  acc[4]+b1.x, acc[5]+b1.y, acc[6]+b1.z, acc[7]+b1.w};
    u32x4 o;
    o.x = f2bf_bits(fmaxf(r[0],0.f)) | (f2bf_bits(fmaxf(r[1],0.f)) << 16);
    o.y = f2bf_bits(fmaxf(r[2],0.f)) | (f2bf_bits(fmaxf(r[3],0.f)) << 16);
    o.z = f2bf_bits(fmaxf(r[4],0.f)) | (f2bf_bits(fmaxf(r[5],0.f)) << 16);
    o.w = f2bf_bits(fmaxf(r[6],0.f)) | (f2bf_bits(fmaxf(r[7],0.f)) << 16);
    __builtin_nontemporal_store(o, ((u32x4*)(H + (size_t)gw * 512)) + lane);
}

// layer 2: out[i] = sum_e norm*T[src] + dinv[i]^2*T[i] + b, D=256, fp32 out.
// TWO nodes per wave (half-wave of 32 lanes x 16B = one 256-elem bf16 row),
// edge loop unrolled x4, non-temporal output store.
__global__ __launch_bounds__(256)
void agg_bias_out_256(const bf16_t* __restrict__ T, const int* __restrict__ rowp,
                      const int* __restrict__ rowe,
                      const int* __restrict__ csrc, const float* __restrict__ cnorm,
                      const float* __restrict__ dinv, const float* __restrict__ bias,
                      float* __restrict__ out)
{
    const int wid  = (blockIdx.x * 256 + threadIdx.x) >> 6;
    const int half = (threadIdx.x >> 5) & 1;
    const int l32  = threadIdx.x & 31;
    const int node = wid * 2 + half;
    if (node >= N_NODES) return;
    const float di = dinv[node];
    float acc[8];
    {
        uint4 v = ((const uint4*)(T + (size_t)node * 256))[l32];
        float f[8]; unpack8(v, f);
        const float w = di * di;
        #pragma unroll
        for (int j = 0; j < 8; ++j) acc[j] = w * f[j];
    }
    int e = rowp[node];
    const int e1 = rowe[node];
    for (; e + 4 <= e1; e += 4){
        const int   s0 = csrc[e],   s1 = csrc[e+1], s2 = csrc[e+2], s3 = csrc[e+3];
        const float w0 = cnorm[e],  w1 = cnorm[e+1], w2 = cnorm[e+2], w3 = cnorm[e+3];
        uint4 v0 = ((const uint4*)(T + (size_t)s0 * 256))[l32];
        uint4 v1 = ((const uint4*)(T + (size_t)s1 * 256))[l32];
        uint4 v2 = ((const uint4*)(T + (size_t)s2 * 256))[l32];
        uint4 v3 = ((const uint4*)(T + (size_t)s3 * 256))[l32];
        float f[8];
        unpack8(v0, f);
        #pragma unroll
        for (int j = 0; j < 8; ++j) acc[j] += w0 * f[j];
        unpack8(v1, f);
        #pragma unroll
        for (int j = 0; j < 8; ++j) acc[j] += w1 * f[j];
        unpack8(v2, f);
        #pragma unroll
        for (int j = 0; j < 8; ++j) acc[j] += w2 * f[j];
        unpack8(v3, f);
        #pragma unroll
        for (int j = 0; j < 8; ++j) acc[j] += w3 * f[j];
    }
    for (; e < e1; ++e){
        const int   s = csrc[e];
        const float w = cnorm[e];
        uint4 v = ((const uint4*)(T + (size_t)s * 256))[l32];
        float f[8]; unpack8(v, f);
        #pragma unroll
        for (int j = 0; j < 8; ++j) acc[j] += w * f[j];
    }
    const float4 b0 = ((const float4*)bias)[l32*2];
    const float4 b1 = ((const float4*)bias)[l32*2 + 1];
    f32x4 o0 = {acc[0]+b0.x, acc[1]+b0.y, acc[2]+b0.z, acc[3]+b0.w};
    f32x4 o1 = {acc[4]+b1.x, acc[5]+b1.y, acc[6]+b1.z, acc[7]+b1.w};
    __builtin_nontemporal_store(o0, ((f32x4*)(out + (size_t)node * 256)) + l32*2);
    __builtin_nontemporal_store(o1, ((f32x4*)(out + (size_t)node * 256)) + l32*2 + 1);
}

// ---------- host ----------
extern "C" void kernel_launch(void* const* d_in, const int* in_sizes, int n_in,
                              void* d_out, int out_size, void* d_ws, size_t ws_size,
                              hipStream_t stream)
{
    const float* x  = (const float*)d_in[0];
    const int*   ei = (const int*)d_in[1];     // [0..4e5)=src, [4e5..8e5)=dst
    const float* W1 = (const float*)d_in[2];
    const float* b1 = (const float*)d_in[3];
    const float* W2 = (const float*)d_in[4];
    const float* b2 = (const float*)d_in[5];
    float* out = (float*)d_out;

    // workspace carve (256B aligned)
    char* w = (char*)d_ws;
    auto alloc = [&](size_t bytes) -> char* {
        char* p = w; w += (bytes + 255) & ~(size_t)255; return p;
    };
    bf16_t* Xb    = (bf16_t*)alloc((size_t)M_PAD * 512 * 2);  // Xb, later reused as H
    bf16_t* T     = (bf16_t*)alloc((size_t)M_PAD * 512 * 2);  // T1, later reused as T2
    bf16_t* W1t   = (bf16_t*)alloc(512 * 512 * 2);
    bf16_t* W2t   = (bf16_t*)alloc(256 * 512 * 2);
    int*    deg   = (int*)  alloc(N_NODES * 4);
    float*  dinv  = (float*)alloc(N_NODES * 4);
    int*    rowp  = (int*)  alloc(N_NODES * 4);
    int*    rowe  = (int*)  alloc(N_NODES * 4);
    int*    cursor= (int*)  alloc(N_NODES * 4);
    int*    csrc  = (int*)  alloc(N_EDGES * 4);
    float*  cnorm = (float*)alloc(N_EDGES * 4);
    int*    cnt   = (int*)  alloc(256);

    // dtype conversion + deg init + counter zero
    conv_x_bf16<<<(M_PAD*128)/256, 256, 0, stream>>>(x, Xb, deg, cnt);
    // weight transposes + edge degree count (grid covers max(768*512, N_EDGES) threads)
    conv_w_both<<<1568, 256, 0, stream>>>(W1, W2, W1t, W2t, ei, deg);

    // CSR build: atomic range reservation (1 kernel) + placement
    k_reserve<<<NB_SCAN, 256, 0, stream>>>(deg, dinv, rowp, rowe, cursor, cnt);
    k_place  <<<(N_EDGES+255)/256, 256, 0, stream>>>(ei, dinv, cursor, csrc, cnorm);

    // layer 1: T1 = Xb @ W1 ; H = relu(agg(T1) + b1)   (H reuses Xb buffer)
    gemm_bf16_mfma<<<dim3(M_PAD/128, 512/128), 256, 0, stream>>>(Xb, W1t, T, 512, 512);
    agg_bias_relu_512<<<6250, 256, 0, stream>>>(T, rowp, rowe, csrc, cnorm, dinv, b1, Xb, 0);
    agg_bias_relu_512<<<6250, 256, 0, stream>>>(T, rowp, rowe, csrc, cnorm, dinv, b1, Xb, 25000);

    // layer 2: T2 = H @ W2 ; out = agg(T2) + b2        (T2 reuses T buffer)
    gemm_bf16_mfma<<<dim3(M_PAD/128, 256/128), 256, 0, stream>>>(Xb, W2t, T, 256, 512);
    agg_bias_out_256<<<(25000+3)/4, 256, 0, stream>>>(T, rowp, rowe, csrc, cnorm, dinv, b2, out);
}

// Round 7
// 404.999 us; speedup vs baseline: 1.0187x; 1.0187x over previous
//
#include <hip/hip_runtime.h>
#include <stdint.h>

typedef __bf16 bf16_t;
typedef __bf16 bf16x8 __attribute__((ext_vector_type(8)));
typedef float f32x4 __attribute__((ext_vector_type(4)));
typedef uint32_t u32x4 __attribute__((ext_vector_type(4)));

#define N_NODES  50000
#define N_EDGES  400000
#define D_IN     512
#define D_HID    512
#define D_OUTD   256
#define M_PAD    50048   // 391 * 128 (GEMM M padded; pad rows zeroed)
#define NB_SCAN  196     // ceil(50000/256)

// ---------- helpers ----------
__device__ __forceinline__ uint32_t f2bf_bits(float x){
    uint32_t u = __float_as_uint(x);
    return (u + 0x7fffu + ((u >> 16) & 1u)) >> 16;   // RNE
}
__device__ __forceinline__ void unpack8(uint4 v, float* f){
    f[0]=__uint_as_float(v.x<<16); f[1]=__uint_as_float(v.x & 0xffff0000u);
    f[2]=__uint_as_float(v.y<<16); f[3]=__uint_as_float(v.y & 0xffff0000u);
    f[4]=__uint_as_float(v.z<<16); f[5]=__uint_as_float(v.z & 0xffff0000u);
    f[6]=__uint_as_float(v.w<<16); f[7]=__uint_as_float(v.w & 0xffff0000u);
}
__device__ __forceinline__ void unpack4(uint2 v, float* f){
    f[0]=__uint_as_float(v.x<<16); f[1]=__uint_as_float(v.x & 0xffff0000u);
    f[2]=__uint_as_float(v.y<<16); f[3]=__uint_as_float(v.y & 0xffff0000u);
}
__device__ __forceinline__ void glds16(const bf16_t* g, bf16_t* l){
    __builtin_amdgcn_global_load_lds(
        (const __attribute__((address_space(1))) uint32_t*)g,
        (__attribute__((address_space(3))) uint32_t*)l, 16, 0, 0);
}

// ---------- dtype conversion (+ deg init + counter zero folded in) ----------
__global__ __launch_bounds__(256)
void conv_x_bf16(const float* __restrict__ x, bf16_t* __restrict__ Xb,
                 int* __restrict__ deg, int* __restrict__ cnt){
    const int t = blockIdx.x * 256 + threadIdx.x;   // 4 elements per thread
    if (t == 0) *cnt = 0;                            // edge-slot counter for k_reserve
    if (t < N_NODES) deg[t] = 1;                    // self-loop degree init
    const int row = t >> 7;                          // (4t)/512
    uint2 o;
    if (row < N_NODES){
        f32x4 v = __builtin_nontemporal_load(((const f32x4*)x) + t);
        o.x = f2bf_bits(v.x) | (f2bf_bits(v.y) << 16);
        o.y = f2bf_bits(v.z) | (f2bf_bits(v.w) << 16);
    } else { o.x = 0u; o.y = 0u; }                   // zero pad rows
    ((uint2*)Xb)[t] = o;
}

// Both weight transposes + edge degree count in one launch.
// grid = 1568 blocks (401408 threads >= max(768*512, N_EDGES))
__global__ __launch_bounds__(256)
void conv_w_both(const float* __restrict__ W1, const float* __restrict__ W2,
                 bf16_t* __restrict__ W1t, bf16_t* __restrict__ W2t,
                 const int* __restrict__ ei, int* __restrict__ deg){
    const int idx = blockIdx.x * 256 + threadIdx.x;  // n*512 + k
    if (idx < N_EDGES) atomicAdd(&deg[ei[N_EDGES + idx]], 1);
    const int n = idx >> 9;
    const int k = idx & 511;
    if (n < 512) W1t[idx] = (bf16_t)W1[k * 512 + n];
    else if (n < 768) W2t[(n - 512) * 512 + k] = (bf16_t)W2[k * 256 + (n - 512)];
}

// ---------- CSR build: single-kernel atomic range reservation ----------
// rowp need NOT be monotonic -- each node just needs a private disjoint slot
// range [rowp[i], rowe[i]). Replaces the 3-kernel scan chain.
__global__ __launch_bounds__(256)
void k_reserve(const int* __restrict__ deg, float* __restrict__ dinv,
               int* __restrict__ rowp, int* __restrict__ rowe,
               int* __restrict__ cursor, int* __restrict__ cnt){
    int i = blockIdx.x*256 + threadIdx.x;
    if (i < N_NODES){
        int d = deg[i];
        dinv[i] = rsqrtf((float)d);
        int r = atomicAdd(cnt, d - 1);
        rowp[i]   = r;
        rowe[i]   = r + d - 1;
        cursor[i] = r;
    }
}
__global__ __launch_bounds__(256)
void k_place(const int* __restrict__ ei, const float* __restrict__ dinv,
             int* __restrict__ cursor, int* __restrict__ csrc, float* __restrict__ cnorm){
    int e = blockIdx.x*256 + threadIdx.x;
    if (e < N_EDGES){
        int s = ei[e];
        int d = ei[N_EDGES + e];
        int p = atomicAdd(&cursor[d], 1);
        csrc[p]  = s;
        cnorm[p] = dinv[s] * dinv[d];
    }
}

// ---------- bf16 MFMA GEMM: C[M_PAD][N] = A[M_PAD][K] @ Bt[N][K]^T ----------
// 128x128 tile, BK=64, 256 threads = 4 waves in 2x2, each wave 64x64 (4x4 MFMA 16x16x32).
// T3+T4 counted-vmcnt pipeline + T2 XOR swizzle (verified r5; memory-bound so
// schedule-invariant on total, kept for correctness-proven state).
__global__ __launch_bounds__(256, 2)
void gemm_bf16_mfma(const bf16_t* __restrict__ A, const bf16_t* __restrict__ Bt,
                    bf16_t* __restrict__ C, int N, int K)
{
    __shared__ bf16_t As[2][128*64];   // 2 x 16 KB
    __shared__ bf16_t Bs[2][128*64];   // 2 x 16 KB

    const int tid  = threadIdx.x;
    const int wave = tid >> 6;
    const int lane = tid & 63;
    const int wr = wave >> 1;
    const int wc = wave & 1;
    const int mBase = blockIdx.x * 128;
    const int nBase = blockIdx.y * 128;

    // staging map: round r (0..3), thread t -> linear LDS slot (r*256+t)*8 elems
    // row = r*32 + wave*8 + (lane>>3); 16B-chunk = (lane&7) ^ (lane>>3) [pre-swizzled src]
    const int sr = lane >> 3;                 // == row & 7
    const int sc = (lane & 7) ^ sr;           // swizzled chunk index
    const bf16_t* Asrc[4]; const bf16_t* Bsrc[4];
    #pragma unroll
    for (int r = 0; r < 4; ++r){
        const int row = r*32 + wave*8 + sr;
        Asrc[r] = A  + (size_t)(mBase + row) * K + sc*8;
        Bsrc[r] = Bt + (size_t)(nBase + row) * K + sc*8;
    }

    auto stage = [&](int k0, int p){
        bf16_t* Ad = &As[p][0];
        bf16_t* Bd = &Bs[p][0];
        #pragma unroll
        for (int r = 0; r < 4; ++r) glds16(Asrc[r] + k0, Ad + (r*256 + tid)*8);
        #pragma unroll
        for (int r = 0; r < 4; ++r) glds16(Bsrc[r] + k0, Bd + (r*256 + tid)*8);
    };

    // fragment addressing: A[m=lane&15][k=kk*32+q*8+j], read addr XOR-swizzled
    const int m16 = lane & 15;
    const int q8  = (lane >> 4) << 3;         // q*8
    const int swz = (m16 & 7) << 3;           // elem-index XOR within a 64-elem row
    const int aBase = (wr*64 + m16)*64;
    const int bBase = (wc*64 + m16)*64;

    f32x4 acc[4][4] = {};

    stage(0, 0);                               // prologue: tile 0 -> buf 0
    const int KT = K >> 6;
    for (int kt = 0; kt < KT; ++kt){
        const int p = kt & 1;
        __builtin_amdgcn_s_barrier();          // B1: all waves done reading buf p^1
        __builtin_amdgcn_sched_barrier(0);
        if (kt + 1 < KT){
            stage((kt + 1) << 6, p ^ 1);       // 8 loads in flight across compute
            asm volatile("s_waitcnt vmcnt(8)" ::: "memory");   // tile kt's 8 oldest done
        } else {
            asm volatile("s_waitcnt vmcnt(0)" ::: "memory");
        }
        __builtin_amdgcn_sched_barrier(0);
        __builtin_amdgcn_s_barrier();          // B2: every wave's tile-kt loads landed
        const bf16_t* Ab = &As[p][0];
        const bf16_t* Bb = &Bs[p][0];
        #pragma unroll
        for (int kk = 0; kk < 2; ++kk){
            const int ko = (kk*32 + q8) ^ swz;
            bf16x8 a[4], b[4];
            #pragma unroll
            for (int t = 0; t < 4; ++t){
                a[t] = *(const bf16x8*)(Ab + aBase + t*1024 + ko);
                b[t] = *(const bf16x8*)(Bb + bBase + t*1024 + ko);
            }
            #pragma unroll
            for (int i = 0; i < 4; ++i){
                #pragma unroll
                for (int j = 0; j < 4; ++j){
                    acc[i][j] = __builtin_amdgcn_mfma_f32_16x16x32_bf16(a[i], b[j], acc[i][j], 0, 0, 0);
                }
            }
        }
    }

    // C/D layout: col = lane&15, row = q*4 + reg  [measured mapping]
    const int qr = lane >> 4;
    #pragma unroll
    for (int i = 0; i < 4; ++i){
        const int row0 = mBase + wr*64 + i*16 + qr*4;
        #pragma unroll
        for (int j = 0; j < 4; ++j){
            const int col = nBase + wc*64 + j*16 + m16;
            bf16_t* Cp = C + (size_t)row0 * N + col;
            #pragma unroll
            for (int r = 0; r < 4; ++r)
                Cp[(size_t)r * N] = (bf16_t)acc[i][j][r];
        }
    }
}

// ---------- aggregation ----------
// layer 1: H[i] = relu(sum_e norm*T[src] + dinv[i]^2*T[i] + b), D=512, bf16 out
// SINGLE dispatch, one wave per node, x4 unroll + serial remainder (measured best).
__global__ __launch_bounds__(256)
void agg_bias_relu_512(const bf16_t* __restrict__ T, const int* __restrict__ rowp,
                       const int* __restrict__ rowe,
                       const int* __restrict__ csrc, const float* __restrict__ cnorm,
                       const float* __restrict__ dinv, const float* __restrict__ bias,
                       bf16_t* __restrict__ H)
{
    const int gw   = (blockIdx.x * 256 + threadIdx.x) >> 6;
    const int lane = threadIdx.x & 63;
    if (gw >= N_NODES) return;
    const float di = dinv[gw];
    float acc[8];
    {
        uint4 v = ((const uint4*)(T + (size_t)gw * 512))[lane];
        float f[8]; unpack8(v, f);
        const float w = di * di;
        #pragma unroll
        for (int j = 0; j < 8; ++j) acc[j] = w * f[j];
    }
    int e = rowp[gw];
    const int e1 = rowe[gw];
    for (; e + 4 <= e1; e += 4){
        const int   s0 = csrc[e],   s1 = csrc[e+1], s2 = csrc[e+2], s3 = csrc[e+3];
        const float w0 = cnorm[e],  w1 = cnorm[e+1], w2 = cnorm[e+2], w3 = cnorm[e+3];
        uint4 v0 = ((const uint4*)(T + (size_t)s0 * 512))[lane];
        uint4 v1 = ((const uint4*)(T + (size_t)s1 * 512))[lane];
        uint4 v2 = ((const uint4*)(T + (size_t)s2 * 512))[lane];
        uint4 v3 = ((const uint4*)(T + (size_t)s3 * 512))[lane];
        float f[8];
        unpack8(v0, f);
        #pragma unroll
        for (int j = 0; j < 8; ++j) acc[j] += w0 * f[j];
        unpack8(v1, f);
        #pragma unroll
        for (int j = 0; j < 8; ++j) acc[j] += w1 * f[j];
        unpack8(v2, f);
        #pragma unroll
        for (int j = 0; j < 8; ++j) acc[j] += w2 * f[j];
        unpack8(v3, f);
        #pragma unroll
        for (int j = 0; j < 8; ++j) acc[j] += w3 * f[j];
    }
    for (; e < e1; ++e){
        const int   s = csrc[e];
        const float w = cnorm[e];
        uint4 v = ((const uint4*)(T + (size_t)s * 512))[lane];
        float f[8]; unpack8(v, f);
        #pragma unroll
        for (int j = 0; j < 8; ++j) acc[j] += w * f[j];
    }
    const float4 b0 = ((const float4*)bias)[lane*2];
    const float4 b1 = ((const float4*)bias)[lane*2 + 1];
    float r[8] = {acc[0]+b0.x, acc[1]+b0.y, acc[2]+b0.z, acc[3]+b0.w,
                  acc[4]+b1.x, acc[5]+b1.y, acc[6]+b1.z, acc[7]+b1.w};
    u32x4 o;
    o.x = f2bf_bits(fmaxf(r[0],0.f)) | (f2bf_bits(fmaxf(r[1],0.f)) << 16);
    o.y = f2bf_bits(fmaxf(r[2],0.f)) | (f2bf_bits(fmaxf(r[3],0.f)) << 16);
    o.z = f2bf_bits(fmaxf(r[4],0.f)) | (f2bf_bits(fmaxf(r[5],0.f)) << 16);
    o.w = f2bf_bits(fmaxf(r[6],0.f)) | (f2bf_bits(fmaxf(r[7],0.f)) << 16);
    __builtin_nontemporal_store(o, ((u32x4*)(H + (size_t)gw * 512)) + lane);
}

// layer 2: out[i] = sum_e norm*T[src] + dinv[i]^2*T[i] + b, D=256, fp32 out.
// ONE node per FULL wave at 8B/lane (64 x uint2 = one 512B bf16 row): removes the
// max(deg_a,deg_b) divergence waste of the old two-nodes-per-wave scheme (~22%).
__global__ __launch_bounds__(256)
void agg_bias_out_256(const bf16_t* __restrict__ T, const int* __restrict__ rowp,
                      const int* __restrict__ rowe,
                      const int* __restrict__ csrc, const float* __restrict__ cnorm,
                      const float* __restrict__ dinv, const float* __restrict__ bias,
                      float* __restrict__ out)
{
    const int node = (blockIdx.x * 256 + threadIdx.x) >> 6;
    const int lane = threadIdx.x & 63;
    if (node >= N_NODES) return;
    const float di = dinv[node];
    const uint2* Tr = (const uint2*)T;      // row s starts at uint2 index s*64
    float acc[4];
    {
        uint2 v = Tr[(size_t)node * 64 + lane];
        float f[4]; unpack4(v, f);
        const float w = di * di;
        #pragma unroll
        for (int j = 0; j < 4; ++j) acc[j] = w * f[j];
    }
    int e = rowp[node];
    const int e1 = rowe[node];
    for (; e + 4 <= e1; e += 4){
        const int   s0 = csrc[e],   s1 = csrc[e+1], s2 = csrc[e+2], s3 = csrc[e+3];
        const float w0 = cnorm[e],  w1 = cnorm[e+1], w2 = cnorm[e+2], w3 = cnorm[e+3];
        uint2 v0 = Tr[(size_t)s0 * 64 + lane];
        uint2 v1 = Tr[(size_t)s1 * 64 + lane];
        uint2 v2 = Tr[(size_t)s2 * 64 + lane];
        uint2 v3 = Tr[(size_t)s3 * 64 + lane];
        float f[4];
        unpack4(v0, f);
        #pragma unroll
        for (int j = 0; j < 4; ++j) acc[j] += w0 * f[j];
        unpack4(v1, f);
        #pragma unroll
        for (int j = 0; j < 4; ++j) acc[j] += w1 * f[j];
        unpack4(v2, f);
        #pragma unroll
        for (int j = 0; j < 4; ++j) acc[j] += w2 * f[j];
        unpack4(v3, f);
        #pragma unroll
        for (int j = 0; j < 4; ++j) acc[j] += w3 * f[j];
    }
    for (; e < e1; ++e){
        const int   s = csrc[e];
        const float w = cnorm[e];
        uint2 v = Tr[(size_t)s * 64 + lane];
        float f[4]; unpack4(v, f);
        #pragma unroll
        for (int j = 0; j < 4; ++j) acc[j] += w * f[j];
    }
    const float4 b = ((const float4*)bias)[lane];
    f32x4 o = {acc[0]+b.x, acc[1]+b.y, acc[2]+b.z, acc[3]+b.w};
    __builtin_nontemporal_store(o, ((f32x4*)(out + (size_t)node * 256)) + lane);
}

// ---------- host ----------
extern "C" void kernel_launch(void* const* d_in, const int* in_sizes, int n_in,
                              void* d_out, int out_size, void* d_ws, size_t ws_size,
                              hipStream_t stream)
{
    const float* x  = (const float*)d_in[0];
    const int*   ei = (const int*)d_in[1];     // [0..4e5)=src, [4e5..8e5)=dst
    const float* W1 = (const float*)d_in[2];
    const float* b1 = (const float*)d_in[3];
    const float* W2 = (const float*)d_in[4];
    const float* b2 = (const float*)d_in[5];
    float* out = (float*)d_out;

    // workspace carve (256B aligned)
    char* w = (char*)d_ws;
    auto alloc = [&](size_t bytes) -> char* {
        char* p = w; w += (bytes + 255) & ~(size_t)255; return p;
    };
    bf16_t* Xb    = (bf16_t*)alloc((size_t)M_PAD * 512 * 2);  // Xb, later reused as H
    bf16_t* T     = (bf16_t*)alloc((size_t)M_PAD * 512 * 2);  // T1, later reused as T2
    bf16_t* W1t   = (bf16_t*)alloc(512 * 512 * 2);
    bf16_t* W2t   = (bf16_t*)alloc(256 * 512 * 2);
    int*    deg   = (int*)  alloc(N_NODES * 4);
    float*  dinv  = (float*)alloc(N_NODES * 4);
    int*    rowp  = (int*)  alloc(N_NODES * 4);
    int*    rowe  = (int*)  alloc(N_NODES * 4);
    int*    cursor= (int*)  alloc(N_NODES * 4);
    int*    csrc  = (int*)  alloc(N_EDGES * 4);
    float*  cnorm = (float*)alloc(N_EDGES * 4);
    int*    cnt   = (int*)  alloc(256);

    // dtype conversion + deg init + counter zero
    conv_x_bf16<<<(M_PAD*128)/256, 256, 0, stream>>>(x, Xb, deg, cnt);
    // weight transposes + edge degree count
    conv_w_both<<<1568, 256, 0, stream>>>(W1, W2, W1t, W2t, ei, deg);

    // CSR build: atomic range reservation (1 kernel) + placement
    k_reserve<<<NB_SCAN, 256, 0, stream>>>(deg, dinv, rowp, rowe, cursor, cnt);
    k_place  <<<(N_EDGES+255)/256, 256, 0, stream>>>(ei, dinv, cursor, csrc, cnorm);

    // layer 1: T1 = Xb @ W1 ; H = relu(agg(T1) + b1)   (H reuses Xb buffer)
    gemm_bf16_mfma<<<dim3(M_PAD/128, 512/128), 256, 0, stream>>>(Xb, W1t, T, 512, 512);
    agg_bias_relu_512<<<(N_NODES+3)/4, 256, 0, stream>>>(T, rowp, rowe, csrc, cnorm, dinv, b1, Xb);

    // layer 2: T2 = H @ W2 ; out = agg(T2) + b2        (T2 reuses T buffer)
    gemm_bf16_mfma<<<dim3(M_PAD/128, 256/128), 256, 0, stream>>>(Xb, W2t, T, 256, 512);
    agg_bias_out_256<<<(N_NODES+3)/4, 256, 0, stream>>>(T, rowp, rowe, csrc, cnorm, dinv, b2, out);
}

// Round 8
// 400.038 us; speedup vs baseline: 1.0313x; 1.0124x over previous
//
#include <hip/hip_runtime.h>
#include <stdint.h>

typedef __bf16 bf16_t;
typedef __bf16 bf16x8 __attribute__((ext_vector_type(8)));
typedef float f32x4 __attribute__((ext_vector_type(4)));
typedef uint32_t u32x4 __attribute__((ext_vector_type(4)));

#define N_NODES  50000
#define N_EDGES  400000
#define D_IN     512
#define D_HID    512
#define D_OUTD   256
#define M_PAD    50048   // 391 * 128 (GEMM M padded; pad rows zeroed)
#define NB_SCAN  196     // ceil(50000/256)

// ---------- helpers ----------
__device__ __forceinline__ uint32_t f2bf_bits(float x){
    uint32_t u = __float_as_uint(x);
    return (u + 0x7fffu + ((u >> 16) & 1u)) >> 16;   // RNE
}
__device__ __forceinline__ void unpack8(uint4 v, float* f){
    f[0]=__uint_as_float(v.x<<16); f[1]=__uint_as_float(v.x & 0xffff0000u);
    f[2]=__uint_as_float(v.y<<16); f[3]=__uint_as_float(v.y & 0xffff0000u);
    f[4]=__uint_as_float(v.z<<16); f[5]=__uint_as_float(v.z & 0xffff0000u);
    f[6]=__uint_as_float(v.w<<16); f[7]=__uint_as_float(v.w & 0xffff0000u);
}
__device__ __forceinline__ void glds16(const bf16_t* g, bf16_t* l){
    __builtin_amdgcn_global_load_lds(
        (const __attribute__((address_space(1))) uint32_t*)g,
        (__attribute__((address_space(3))) uint32_t*)l, 16, 0, 0);
}

// ---------- dtype conversion (+ deg init folded in) ----------
__global__ __launch_bounds__(256)
void conv_x_bf16(const float* __restrict__ x, bf16_t* __restrict__ Xb,
                 int* __restrict__ deg){
    const int t = blockIdx.x * 256 + threadIdx.x;   // 4 elements per thread
    if (t < N_NODES) deg[t] = 1;                    // self-loop degree init
    const int row = t >> 7;                          // (4t)/512
    uint2 o;
    if (row < N_NODES){
        f32x4 v = __builtin_nontemporal_load(((const f32x4*)x) + t);
        o.x = f2bf_bits(v.x) | (f2bf_bits(v.y) << 16);
        o.y = f2bf_bits(v.z) | (f2bf_bits(v.w) << 16);
    } else { o.x = 0u; o.y = 0u; }                   // zero pad rows
    ((uint2*)Xb)[t] = o;
}

// Both weight transposes + edge degree count in one launch.
// grid = 1568 blocks (401408 threads >= max(768*512, N_EDGES))
__global__ __launch_bounds__(256)
void conv_w_both(const float* __restrict__ W1, const float* __restrict__ W2,
                 bf16_t* __restrict__ W1t, bf16_t* __restrict__ W2t,
                 const int* __restrict__ ei, int* __restrict__ deg){
    const int idx = blockIdx.x * 256 + threadIdx.x;  // n*512 + k
    if (idx < N_EDGES) atomicAdd(&deg[ei[N_EDGES + idx]], 1);
    const int n = idx >> 9;
    const int k = idx & 511;
    if (n < 512) W1t[idx] = (bf16_t)W1[k * 512 + n];
    else if (n < 768) W2t[(n - 512) * 512 + k] = (bf16_t)W2[k * 256 + (n - 512)];
}

// ---------- CSR build (scan chain — r5 proven) ----------
__global__ __launch_bounds__(256)
void k_scan_dinv(const int* __restrict__ deg, float* __restrict__ dinv,
                 int* __restrict__ part, int* __restrict__ bsum, int n){
    __shared__ int tmp[256];
    int i = blockIdx.x*256 + threadIdx.x;
    int d = (i < n) ? deg[i] : 1;
    if (i < n) dinv[i] = rsqrtf((float)d);
    int v = (i < n) ? (d - 1) : 0;
    tmp[threadIdx.x] = v;
    __syncthreads();
    for (int off = 1; off < 256; off <<= 1){
        int t = (threadIdx.x >= off) ? tmp[threadIdx.x - off] : 0;
        __syncthreads();
        tmp[threadIdx.x] += t;
        __syncthreads();
    }
    if (i < n) part[i] = tmp[threadIdx.x] - v;
    if (threadIdx.x == 255) bsum[blockIdx.x] = tmp[255];
}
__global__ __launch_bounds__(256)
void k_scan_bsum(const int* __restrict__ bsum, int* __restrict__ bsum2, int nb){
    __shared__ int tmp[256];
    int v = (threadIdx.x < nb) ? bsum[threadIdx.x] : 0;
    tmp[threadIdx.x] = v;
    __syncthreads();
    for (int off = 1; off < 256; off <<= 1){
        int t = (threadIdx.x >= off) ? tmp[threadIdx.x - off] : 0;
        __syncthreads();
        tmp[threadIdx.x] += t;
        __syncthreads();
    }
    if (threadIdx.x < nb) bsum2[threadIdx.x] = tmp[threadIdx.x] - v;
}
__global__ __launch_bounds__(256)
void k_finalize_rowptr(const int* __restrict__ part, const int* __restrict__ bsum2,
                       int* __restrict__ rowp, int* __restrict__ cursor, int n){
    int i = blockIdx.x*256 + threadIdx.x;
    if (i < n){ int r = part[i] + bsum2[blockIdx.x]; rowp[i] = r; cursor[i] = r; }
    if (i == 0) rowp[n] = N_EDGES;
}
__global__ __launch_bounds__(256)
void k_place(const int* __restrict__ ei, const float* __restrict__ dinv,
             int* __restrict__ cursor, int* __restrict__ csrc, float* __restrict__ cnorm){
    int e = blockIdx.x*256 + threadIdx.x;
    if (e < N_EDGES){
        int s = ei[e];
        int d = ei[N_EDGES + e];
        int p = atomicAdd(&cursor[d], 1);
        csrc[p]  = s;
        cnorm[p] = dinv[s] * dinv[d];
    }
}

// ---------- bf16 MFMA GEMM: C[M_PAD][N] = A[M_PAD][K] @ Bt[N][K]^T ----------
// 128x128 tile, BK=64, 4 waves 2x2; counted-vmcnt pipeline + XOR swizzle (r5 proven).
__global__ __launch_bounds__(256, 2)
void gemm_bf16_mfma(const bf16_t* __restrict__ A, const bf16_t* __restrict__ Bt,
                    bf16_t* __restrict__ C, int N, int K)
{
    __shared__ bf16_t As[2][128*64];   // 2 x 16 KB
    __shared__ bf16_t Bs[2][128*64];   // 2 x 16 KB

    const int tid  = threadIdx.x;
    const int wave = tid >> 6;
    const int lane = tid & 63;
    const int wr = wave >> 1;
    const int wc = wave & 1;
    const int mBase = blockIdx.x * 128;
    const int nBase = blockIdx.y * 128;

    const int sr = lane >> 3;                 // == row & 7
    const int sc = (lane & 7) ^ sr;           // swizzled chunk index
    const bf16_t* Asrc[4]; const bf16_t* Bsrc[4];
    #pragma unroll
    for (int r = 0; r < 4; ++r){
        const int row = r*32 + wave*8 + sr;
        Asrc[r] = A  + (size_t)(mBase + row) * K + sc*8;
        Bsrc[r] = Bt + (size_t)(nBase + row) * K + sc*8;
    }

    auto stage = [&](int k0, int p){
        bf16_t* Ad = &As[p][0];
        bf16_t* Bd = &Bs[p][0];
        #pragma unroll
        for (int r = 0; r < 4; ++r) glds16(Asrc[r] + k0, Ad + (r*256 + tid)*8);
        #pragma unroll
        for (int r = 0; r < 4; ++r) glds16(Bsrc[r] + k0, Bd + (r*256 + tid)*8);
    };

    const int m16 = lane & 15;
    const int q8  = (lane >> 4) << 3;         // q*8
    const int swz = (m16 & 7) << 3;           // elem-index XOR within a 64-elem row
    const int aBase = (wr*64 + m16)*64;
    const int bBase = (wc*64 + m16)*64;

    f32x4 acc[4][4] = {};

    stage(0, 0);                               // prologue: tile 0 -> buf 0
    const int KT = K >> 6;
    for (int kt = 0; kt < KT; ++kt){
        const int p = kt & 1;
        __builtin_amdgcn_s_barrier();          // B1: all waves done reading buf p^1
        __builtin_amdgcn_sched_barrier(0);
        if (kt + 1 < KT){
            stage((kt + 1) << 6, p ^ 1);       // 8 loads in flight across compute
            asm volatile("s_waitcnt vmcnt(8)" ::: "memory");   // tile kt's 8 oldest done
        } else {
            asm volatile("s_waitcnt vmcnt(0)" ::: "memory");
        }
        __builtin_amdgcn_sched_barrier(0);
        __builtin_amdgcn_s_barrier();          // B2: every wave's tile-kt loads landed
        const bf16_t* Ab = &As[p][0];
        const bf16_t* Bb = &Bs[p][0];
        #pragma unroll
        for (int kk = 0; kk < 2; ++kk){
            const int ko = (kk*32 + q8) ^ swz;
            bf16x8 a[4], b[4];
            #pragma unroll
            for (int t = 0; t < 4; ++t){
                a[t] = *(const bf16x8*)(Ab + aBase + t*1024 + ko);
                b[t] = *(const bf16x8*)(Bb + bBase + t*1024 + ko);
            }
            #pragma unroll
            for (int i = 0; i < 4; ++i){
                #pragma unroll
                for (int j = 0; j < 4; ++j){
                    acc[i][j] = __builtin_amdgcn_mfma_f32_16x16x32_bf16(a[i], b[j], acc[i][j], 0, 0, 0);
                }
            }
        }
    }

    // C/D layout: col = lane&15, row = q*4 + reg  [measured mapping]
    const int qr = lane >> 4;
    #pragma unroll
    for (int i = 0; i < 4; ++i){
        const int row0 = mBase + wr*64 + i*16 + qr*4;
        #pragma unroll
        for (int j = 0; j < 4; ++j){
            const int col = nBase + wc*64 + j*16 + m16;
            bf16_t* Cp = C + (size_t)row0 * N + col;
            #pragma unroll
            for (int r = 0; r < 4; ++r)
                Cp[(size_t)r * N] = (bf16_t)acc[i][j][r];
        }
    }
}

// ---------- aggregation ----------
// layer 1: H[i] = relu(sum_e norm*T[src] + dinv[i]^2*T[i] + b), D=512, bf16 out.
// One wave per node. ROTATE PIPELINE: batch k+1's 4 gathers are issued BEFORE
// accumulating batch k, so the compiler waits vmcnt(4) not vmcnt(0) -- gather
// latency hides under the ~100 VALU ops of accumulation. 8 loads in flight,
// zero wasted lanes (vs r3's clamped 8-wide batch which cost VALU+occupancy).
__global__ __launch_bounds__(256)
void agg_bias_relu_512(const bf16_t* __restrict__ T, const int* __restrict__ rowp,
                       const int* __restrict__ csrc, const float* __restrict__ cnorm,
                       const float* __restrict__ dinv, const float* __restrict__ bias,
                       bf16_t* __restrict__ H)
{
    const int gw   = (blockIdx.x * 256 + threadIdx.x) >> 6;
    const int lane = threadIdx.x & 63;
    if (gw >= N_NODES) return;
    const float di = dinv[gw];
    const uint4* Tr = (const uint4*)T;      // row s at uint4 index s*64
    float acc[8];
    {
        uint4 v = Tr[(size_t)gw * 64 + lane];
        float f[8]; unpack8(v, f);
        const float w = di * di;
        #pragma unroll
        for (int j = 0; j < 8; ++j) acc[j] = w * f[j];
    }
    int e = rowp[gw];
    const int e1 = rowp[gw + 1];

    if (e + 4 <= e1){
        // prologue: issue batch 0
        uint4 v0, v1, v2, v3; float w0, w1, w2, w3;
        {
            const int s0 = csrc[e], s1 = csrc[e+1], s2 = csrc[e+2], s3 = csrc[e+3];
            w0 = cnorm[e]; w1 = cnorm[e+1]; w2 = cnorm[e+2]; w3 = cnorm[e+3];
            v0 = Tr[(size_t)s0 * 64 + lane];
            v1 = Tr[(size_t)s1 * 64 + lane];
            v2 = Tr[(size_t)s2 * 64 + lane];
            v3 = Tr[(size_t)s3 * 64 + lane];
        }
        e += 4;
        for (; e + 4 <= e1; e += 4){
            // issue NEXT batch first (keeps 8 gathers outstanding)
            const int   t0 = csrc[e],   t1 = csrc[e+1], t2 = csrc[e+2], t3 = csrc[e+3];
            const float x0 = cnorm[e],  x1 = cnorm[e+1], x2 = cnorm[e+2], x3 = cnorm[e+3];
            uint4 n0 = Tr[(size_t)t0 * 64 + lane];
            uint4 n1 = Tr[(size_t)t1 * 64 + lane];
            uint4 n2 = Tr[(size_t)t2 * 64 + lane];
            uint4 n3 = Tr[(size_t)t3 * 64 + lane];
            // accumulate CURRENT batch (waits vmcnt(4), not 0)
            float f[8];
            unpack8(v0, f);
            #pragma unroll
            for (int j = 0; j < 8; ++j) acc[j] += w0 * f[j];
            unpack8(v1, f);
            #pragma unroll
            for (int j = 0; j < 8; ++j) acc[j] += w1 * f[j];
            unpack8(v2, f);
            #pragma unroll
            for (int j = 0; j < 8; ++j) acc[j] += w2 * f[j];
            unpack8(v3, f);
            #pragma unroll
            for (int j = 0; j < 8; ++j) acc[j] += w3 * f[j];
            v0 = n0; v1 = n1; v2 = n2; v3 = n3;
            w0 = x0; w1 = x1; w2 = x2; w3 = x3;
        }
        // drain final full batch
        float f[8];
        unpack8(v0, f);
        #pragma unroll
        for (int j = 0; j < 8; ++j) acc[j] += w0 * f[j];
        unpack8(v1, f);
        #pragma unroll
        for (int j = 0; j < 8; ++j) acc[j] += w1 * f[j];
        unpack8(v2, f);
        #pragma unroll
        for (int j = 0; j < 8; ++j) acc[j] += w2 * f[j];
        unpack8(v3, f);
        #pragma unroll
        for (int j = 0; j < 8; ++j) acc[j] += w3 * f[j];
    }
    for (; e < e1; ++e){
        const int   s = csrc[e];
        const float w = cnorm[e];
        uint4 v = Tr[(size_t)s * 64 + lane];
        float f[8]; unpack8(v, f);
        #pragma unroll
        for (int j = 0; j < 8; ++j) acc[j] += w * f[j];
    }
    const float4 b0 = ((const float4*)bias)[lane*2];
    const float4 b1 = ((const float4*)bias)[lane*2 + 1];
    float r[8] = {acc[0]+b0.x, acc[1]+b0.y, acc[2]+b0.z, acc[3]+b0.w,
                  acc[4]+b1.x, acc[5]+b1.y, acc[6]+b1.z, acc[7]+b1.w};
    u32x4 o;
    o.x = f2bf_bits(fmaxf(r[0],0.f)) | (f2bf_bits(fmaxf(r[1],0.f)) << 16);
    o.y = f2bf_bits(fmaxf(r[2],0.f)) | (f2bf_bits(fmaxf(r[3],0.f)) << 16);
    o.z = f2bf_bits(fmaxf(r[4],0.f)) | (f2bf_bits(fmaxf(r[5],0.f)) << 16);
    o.w = f2bf_bits(fmaxf(r[6],0.f)) | (f2bf_bits(fmaxf(r[7],0.f)) << 16);
    __builtin_nontemporal_store(o, ((u32x4*)(H + (size_t)gw * 512)) + lane);
}

// layer 2: out[i] = sum_e norm*T[src] + dinv[i]^2*T[i] + b, D=256, fp32 out.
// TWO nodes per wave (r5 proven layout), x4 unroll + serial remainder.
__global__ __launch_bounds__(256)
void agg_bias_out_256(const bf16_t* __restrict__ T, const int* __restrict__ rowp,
                      const int* __restrict__ csrc, const float* __restrict__ cnorm,
                      const float* __restrict__ dinv, const float* __restrict__ bias,
                      float* __restrict__ out)
{
    const int wid  = (blockIdx.x * 256 + threadIdx.x) >> 6;
    const int half = (threadIdx.x >> 5) & 1;
    const int l32  = threadIdx.x & 31;
    const int node = wid * 2 + half;
    if (node >= N_NODES) return;
    const float di = dinv[node];
    float acc[8];
    {
        uint4 v = ((const uint4*)(T + (size_t)node * 256))[l32];
        float f[8]; unpack8(v, f);
        const float w = di * di;
        #pragma unroll
        for (int j = 0; j < 8; ++j) acc[j] = w * f[j];
    }
    int e = rowp[node];
    const int e1 = rowp[node + 1];
    for (; e + 4 <= e1; e += 4){
        const int   s0 = csrc[e],   s1 = csrc[e+1], s2 = csrc[e+2], s3 = csrc[e+3];
        const float w0 = cnorm[e],  w1 = cnorm[e+1], w2 = cnorm[e+2], w3 = cnorm[e+3];
        uint4 v0 = ((const uint4*)(T + (size_t)s0 * 256))[l32];
        uint4 v1 = ((const uint4*)(T + (size_t)s1 * 256))[l32];
        uint4 v2 = ((const uint4*)(T + (size_t)s2 * 256))[l32];
        uint4 v3 = ((const uint4*)(T + (size_t)s3 * 256))[l32];
        float f[8];
        unpack8(v0, f);
        #pragma unroll
        for (int j = 0; j < 8; ++j) acc[j] += w0 * f[j];
        unpack8(v1, f);
        #pragma unroll
        for (int j = 0; j < 8; ++j) acc[j] += w1 * f[j];
        unpack8(v2, f);
        #pragma unroll
        for (int j = 0; j < 8; ++j) acc[j] += w2 * f[j];
        unpack8(v3, f);
        #pragma unroll
        for (int j = 0; j < 8; ++j) acc[j] += w3 * f[j];
    }
    for (; e < e1; ++e){
        const int   s = csrc[e];
        const float w = cnorm[e];
        uint4 v = ((const uint4*)(T + (size_t)s * 256))[l32];
        float f[8]; unpack8(v, f);
        #pragma unroll
        for (int j = 0; j < 8; ++j) acc[j] += w * f[j];
    }
    const float4 b0 = ((const float4*)bias)[l32*2];
    const float4 b1 = ((const float4*)bias)[l32*2 + 1];
    f32x4 o0 = {acc[0]+b0.x, acc[1]+b0.y, acc[2]+b0.z, acc[3]+b0.w};
    f32x4 o1 = {acc[4]+b1.x, acc[5]+b1.y, acc[6]+b1.z, acc[7]+b1.w};
    __builtin_nontemporal_store(o0, ((f32x4*)(out + (size_t)node * 256)) + l32*2);
    __builtin_nontemporal_store(o1, ((f32x4*)(out + (size_t)node * 256)) + l32*2 + 1);
}

// ---------- host ----------
extern "C" void kernel_launch(void* const* d_in, const int* in_sizes, int n_in,
                              void* d_out, int out_size, void* d_ws, size_t ws_size,
                              hipStream_t stream)
{
    const float* x  = (const float*)d_in[0];
    const int*   ei = (const int*)d_in[1];     // [0..4e5)=src, [4e5..8e5)=dst
    const float* W1 = (const float*)d_in[2];
    const float* b1 = (const float*)d_in[3];
    const float* W2 = (const float*)d_in[4];
    const float* b2 = (const float*)d_in[5];
    float* out = (float*)d_out;

    // workspace carve (256B aligned)
    char* w = (char*)d_ws;
    auto alloc = [&](size_t bytes) -> char* {
        char* p = w; w += (bytes + 255) & ~(size_t)255; return p;
    };
    bf16_t* Xb    = (bf16_t*)alloc((size_t)M_PAD * 512 * 2);  // Xb, later reused as H
    bf16_t* T     = (bf16_t*)alloc((size_t)M_PAD * 512 * 2);  // T1, later reused as T2
    bf16_t* W1t   = (bf16_t*)alloc(512 * 512 * 2);
    bf16_t* W2t   = (bf16_t*)alloc(256 * 512 * 2);
    int*    deg   = (int*)  alloc(N_NODES * 4);
    float*  dinv  = (float*)alloc(N_NODES * 4);
    int*    rowp  = (int*)  alloc((N_NODES + 1) * 4);
    int*    cursor= (int*)  alloc(N_NODES * 4);
    int*    part  = (int*)  alloc(N_NODES * 4);
    int*    bsum  = (int*)  alloc(NB_SCAN * 4);
    int*    bsum2 = (int*)  alloc(NB_SCAN * 4);
    int*    csrc  = (int*)  alloc(N_EDGES * 4);
    float*  cnorm = (float*)alloc(N_EDGES * 4);

    // dtype conversion + deg init
    conv_x_bf16<<<(M_PAD*128)/256, 256, 0, stream>>>(x, Xb, deg);
    // weight transposes + edge degree count
    conv_w_both<<<1568, 256, 0, stream>>>(W1, W2, W1t, W2t, ei, deg);

    // CSR build (scan chain — r5 proven)
    k_scan_dinv<<<NB_SCAN, 256, 0, stream>>>(deg, dinv, part, bsum, N_NODES);
    k_scan_bsum <<<1, 256, 0, stream>>>(bsum, bsum2, NB_SCAN);
    k_finalize_rowptr<<<NB_SCAN, 256, 0, stream>>>(part, bsum2, rowp, cursor, N_NODES);
    k_place   <<<(N_EDGES+255)/256, 256, 0, stream>>>(ei, dinv, cursor, csrc, cnorm);

    // layer 1: T1 = Xb @ W1 ; H = relu(agg(T1) + b1)   (H reuses Xb buffer)
    gemm_bf16_mfma<<<dim3(M_PAD/128, 512/128), 256, 0, stream>>>(Xb, W1t, T, 512, 512);
    agg_bias_relu_512<<<(N_NODES+3)/4, 256, 0, stream>>>(T, rowp, csrc, cnorm, dinv, b1, Xb);

    // layer 2: T2 = H @ W2 ; out = agg(T2) + b2        (T2 reuses T buffer)
    gemm_bf16_mfma<<<dim3(M_PAD/128, 256/128), 256, 0, stream>>>(Xb, W2t, T, 256, 512);
    agg_bias_out_256<<<(25000+3)/4, 256, 0, stream>>>(T, rowp, csrc, cnorm, dinv, b2, out);
}

// Round 9
// 392.471 us; speedup vs baseline: 1.0512x; 1.0193x over previous
//
#include <hip/hip_runtime.h>
#include <stdint.h>

typedef __bf16 bf16_t;
typedef __bf16 bf16x8 __attribute__((ext_vector_type(8)));
typedef float f32x4 __attribute__((ext_vector_type(4)));
typedef uint32_t u32x4 __attribute__((ext_vector_type(4)));

#define N_NODES  50000
#define N_EDGES  400000
#define D_IN     512
#define D_HID    512
#define D_OUTD   256
#define M_PAD    50048   // 391 * 128 (GEMM M padded; pad rows zeroed)
#define NB_SCAN  196     // ceil(50000/256)

// ---------- helpers ----------
__device__ __forceinline__ uint32_t f2bf_bits(float x){
    uint32_t u = __float_as_uint(x);
    return (u + 0x7fffu + ((u >> 16) & 1u)) >> 16;   // RNE
}
__device__ __forceinline__ void unpack8(uint4 v, float* f){
    f[0]=__uint_as_float(v.x<<16); f[1]=__uint_as_float(v.x & 0xffff0000u);
    f[2]=__uint_as_float(v.y<<16); f[3]=__uint_as_float(v.y & 0xffff0000u);
    f[4]=__uint_as_float(v.z<<16); f[5]=__uint_as_float(v.z & 0xffff0000u);
    f[6]=__uint_as_float(v.w<<16); f[7]=__uint_as_float(v.w & 0xffff0000u);
}
__device__ __forceinline__ void glds16(const bf16_t* g, bf16_t* l){
    __builtin_amdgcn_global_load_lds(
        (const __attribute__((address_space(1))) uint32_t*)g,
        (__attribute__((address_space(3))) uint32_t*)l, 16, 0, 0);
}

// ---------- dtype conversion (+ deg init folded in) ----------
__global__ __launch_bounds__(256)
void conv_x_bf16(const float* __restrict__ x, bf16_t* __restrict__ Xb,
                 int* __restrict__ deg){
    const int t = blockIdx.x * 256 + threadIdx.x;   // 4 elements per thread
    if (t < N_NODES) deg[t] = 1;                    // self-loop degree init
    const int row = t >> 7;                          // (4t)/512
    uint2 o;
    if (row < N_NODES){
        f32x4 v = __builtin_nontemporal_load(((const f32x4*)x) + t);
        o.x = f2bf_bits(v.x) | (f2bf_bits(v.y) << 16);
        o.y = f2bf_bits(v.z) | (f2bf_bits(v.w) << 16);
    } else { o.x = 0u; o.y = 0u; }                   // zero pad rows
    ((uint2*)Xb)[t] = o;
}

// Both weight transposes + edge degree count in one launch.
// grid = 1568 blocks (401408 threads >= max(768*512, N_EDGES))
__global__ __launch_bounds__(256)
void conv_w_both(const float* __restrict__ W1, const float* __restrict__ W2,
                 bf16_t* __restrict__ W1t, bf16_t* __restrict__ W2t,
                 const int* __restrict__ ei, int* __restrict__ deg){
    const int idx = blockIdx.x * 256 + threadIdx.x;  // n*512 + k
    if (idx < N_EDGES) atomicAdd(&deg[ei[N_EDGES + idx]], 1);
    const int n = idx >> 9;
    const int k = idx & 511;
    if (n < 512) W1t[idx] = (bf16_t)W1[k * 512 + n];
    else if (n < 768) W2t[(n - 512) * 512 + k] = (bf16_t)W2[k * 256 + (n - 512)];
}

// ---------- CSR build (scan chain — proven) ----------
__global__ __launch_bounds__(256)
void k_scan_dinv(const int* __restrict__ deg, float* __restrict__ dinv,
                 int* __restrict__ part, int* __restrict__ bsum, int n){
    __shared__ int tmp[256];
    int i = blockIdx.x*256 + threadIdx.x;
    int d = (i < n) ? deg[i] : 1;
    if (i < n) dinv[i] = rsqrtf((float)d);
    int v = (i < n) ? (d - 1) : 0;
    tmp[threadIdx.x] = v;
    __syncthreads();
    for (int off = 1; off < 256; off <<= 1){
        int t = (threadIdx.x >= off) ? tmp[threadIdx.x - off] : 0;
        __syncthreads();
        tmp[threadIdx.x] += t;
        __syncthreads();
    }
    if (i < n) part[i] = tmp[threadIdx.x] - v;
    if (threadIdx.x == 255) bsum[blockIdx.x] = tmp[255];
}
__global__ __launch_bounds__(256)
void k_scan_bsum(const int* __restrict__ bsum, int* __restrict__ bsum2, int nb){
    __shared__ int tmp[256];
    int v = (threadIdx.x < nb) ? bsum[threadIdx.x] : 0;
    tmp[threadIdx.x] = v;
    __syncthreads();
    for (int off = 1; off < 256; off <<= 1){
        int t = (threadIdx.x >= off) ? tmp[threadIdx.x - off] : 0;
        __syncthreads();
        tmp[threadIdx.x] += t;
        __syncthreads();
    }
    if (threadIdx.x < nb) bsum2[threadIdx.x] = tmp[threadIdx.x] - v;
}
__global__ __launch_bounds__(256)
void k_finalize_rowptr(const int* __restrict__ part, const int* __restrict__ bsum2,
                       int* __restrict__ rowp, int* __restrict__ cursor, int n){
    int i = blockIdx.x*256 + threadIdx.x;
    if (i < n){ int r = part[i] + bsum2[blockIdx.x]; rowp[i] = r; cursor[i] = r; }
    if (i == 0) rowp[n] = N_EDGES;
}
__global__ __launch_bounds__(256)
void k_place(const int* __restrict__ ei, const float* __restrict__ dinv,
             int* __restrict__ cursor, int* __restrict__ csrc, float* __restrict__ cnorm){
    int e = blockIdx.x*256 + threadIdx.x;
    if (e < N_EDGES){
        int s = ei[e];
        int d = ei[N_EDGES + e];
        int p = atomicAdd(&cursor[d], 1);
        csrc[p]  = s;
        cnorm[p] = dinv[s] * dinv[d];
    }
}

// ---------- bf16 MFMA GEMM: C[M_PAD][N] = A[M_PAD][K] @ Bt[N][K]^T ----------
// 128x256 tile, BK=32, 256 threads = 4 waves in 2x2 (each wave 64 rows x 128 cols,
// 4x8 MFMA 16x16x32). WIDER N-TILE halves A re-reads (the GEMM is BW-bound:
// three different schedules tied, so traffic -- not scheduling -- is the lever).
// Simple 2-barrier schedule (schedule-invariance proven r2/r4/r5).
__global__ __launch_bounds__(256, 2)
void gemm_bf16_mfma(const bf16_t* __restrict__ A, const bf16_t* __restrict__ Bt,
                    bf16_t* __restrict__ C, int N, int K)
{
    __shared__ bf16_t As[128*32];   // [m][k], 8 KB
    __shared__ bf16_t Bs[256*32];   // [n][k], 16 KB

    const int tid  = threadIdx.x;
    const int lane = tid & 63;
    const int wave = tid >> 6;
    const int wr = wave >> 1;       // 0..1: row half
    const int wc = wave & 1;        // 0..1: col half (128 cols each)
    const int mBase = blockIdx.x * 128;
    const int nBase = blockIdx.y * 256;

    // staging: flat map, call c: slot (c*256+t)*8 elems; row=(c*256+t)>>2, col8=(t&3)*8
    const int srow = tid >> 2;            // 0..63 within a 256-thread call
    const int scol = (tid & 3) << 3;
    const bf16_t* Ag0 = A  + (size_t)(mBase + srow) * K + scol;        // call 0: rows 0..63
    const bf16_t* Ag1 = A  + (size_t)(mBase + 64 + srow) * K + scol;   // call 1: rows 64..127
    const bf16_t* Bg[4];
    #pragma unroll
    for (int c = 0; c < 4; ++c)
        Bg[c] = Bt + (size_t)(nBase + c*64 + srow) * K + scol;

    // fragment addressing: A[m=lane&15][k=q*8+j], B[k][n=lane&15]
    const int m16 = lane & 15;
    const int q   = lane >> 4;
    const bf16_t* aP = &As[(wr*64 + m16)*32 + q*8];
    const bf16_t* bP = &Bs[(wc*128 + m16)*32 + q*8];

    f32x4 acc[4][8] = {};

    for (int k0 = 0; k0 < K; k0 += 32){
        glds16(Ag0 + k0, &As[(size_t)tid * 8]);
        glds16(Ag1 + k0, &As[(size_t)(256 + tid) * 8]);
        #pragma unroll
        for (int c = 0; c < 4; ++c)
            glds16(Bg[c] + k0, &Bs[(size_t)(c*256 + tid) * 8]);
        __syncthreads();           // drains vmcnt for global_load_lds
        bf16x8 a[4], b[8];
        #pragma unroll
        for (int t = 0; t < 4; ++t) a[t] = *(const bf16x8*)(aP + t*16*32);
        #pragma unroll
        for (int t = 0; t < 8; ++t) b[t] = *(const bf16x8*)(bP + t*16*32);
        #pragma unroll
        for (int i = 0; i < 4; ++i){
            #pragma unroll
            for (int j = 0; j < 8; ++j){
                acc[i][j] = __builtin_amdgcn_mfma_f32_16x16x32_bf16(a[i], b[j], acc[i][j], 0, 0, 0);
            }
        }
        __syncthreads();
    }

    // C/D layout: col = lane&15, row = q*4 + reg  [measured mapping]
    #pragma unroll
    for (int i = 0; i < 4; ++i){
        const int row0 = mBase + wr*64 + i*16 + q*4;
        #pragma unroll
        for (int j = 0; j < 8; ++j){
            const int col = nBase + wc*128 + j*16 + m16;
            bf16_t* Cp = C + (size_t)row0 * N + col;
            #pragma unroll
            for (int r = 0; r < 4; ++r)
                Cp[(size_t)r * N] = (bf16_t)acc[i][j][r];
        }
    }
}

// ---------- aggregation ----------
// layer 1: H[i] = relu(sum_e norm*T[src] + dinv[i]^2*T[i] + b), D=512, bf16 out.
// One wave per node, rotate pipeline (r8: batch k+1 issued before accumulating k).
__global__ __launch_bounds__(256)
void agg_bias_relu_512(const bf16_t* __restrict__ T, const int* __restrict__ rowp,
                       const int* __restrict__ csrc, const float* __restrict__ cnorm,
                       const float* __restrict__ dinv, const float* __restrict__ bias,
                       bf16_t* __restrict__ H)
{
    const int gw   = (blockIdx.x * 256 + threadIdx.x) >> 6;
    const int lane = threadIdx.x & 63;
    if (gw >= N_NODES) return;
    const float di = dinv[gw];
    const uint4* Tr = (const uint4*)T;      // row s at uint4 index s*64
    float acc[8];
    {
        uint4 v = Tr[(size_t)gw * 64 + lane];
        float f[8]; unpack8(v, f);
        const float w = di * di;
        #pragma unroll
        for (int j = 0; j < 8; ++j) acc[j] = w * f[j];
    }
    int e = rowp[gw];
    const int e1 = rowp[gw + 1];

    if (e + 4 <= e1){
        uint4 v0, v1, v2, v3; float w0, w1, w2, w3;
        {
            const int s0 = csrc[e], s1 = csrc[e+1], s2 = csrc[e+2], s3 = csrc[e+3];
            w0 = cnorm[e]; w1 = cnorm[e+1]; w2 = cnorm[e+2]; w3 = cnorm[e+3];
            v0 = Tr[(size_t)s0 * 64 + lane];
            v1 = Tr[(size_t)s1 * 64 + lane];
            v2 = Tr[(size_t)s2 * 64 + lane];
            v3 = Tr[(size_t)s3 * 64 + lane];
        }
        e += 4;
        for (; e + 4 <= e1; e += 4){
            const int   t0 = csrc[e],   t1 = csrc[e+1], t2 = csrc[e+2], t3 = csrc[e+3];
            const float x0 = cnorm[e],  x1 = cnorm[e+1], x2 = cnorm[e+2], x3 = cnorm[e+3];
            uint4 n0 = Tr[(size_t)t0 * 64 + lane];
            uint4 n1 = Tr[(size_t)t1 * 64 + lane];
            uint4 n2 = Tr[(size_t)t2 * 64 + lane];
            uint4 n3 = Tr[(size_t)t3 * 64 + lane];
            float f[8];
            unpack8(v0, f);
            #pragma unroll
            for (int j = 0; j < 8; ++j) acc[j] += w0 * f[j];
            unpack8(v1, f);
            #pragma unroll
            for (int j = 0; j < 8; ++j) acc[j] += w1 * f[j];
            unpack8(v2, f);
            #pragma unroll
            for (int j = 0; j < 8; ++j) acc[j] += w2 * f[j];
            unpack8(v3, f);
            #pragma unroll
            for (int j = 0; j < 8; ++j) acc[j] += w3 * f[j];
            v0 = n0; v1 = n1; v2 = n2; v3 = n3;
            w0 = x0; w1 = x1; w2 = x2; w3 = x3;
        }
        float f[8];
        unpack8(v0, f);
        #pragma unroll
        for (int j = 0; j < 8; ++j) acc[j] += w0 * f[j];
        unpack8(v1, f);
        #pragma unroll
        for (int j = 0; j < 8; ++j) acc[j] += w1 * f[j];
        unpack8(v2, f);
        #pragma unroll
        for (int j = 0; j < 8; ++j) acc[j] += w2 * f[j];
        unpack8(v3, f);
        #pragma unroll
        for (int j = 0; j < 8; ++j) acc[j] += w3 * f[j];
    }
    for (; e < e1; ++e){
        const int   s = csrc[e];
        const float w = cnorm[e];
        uint4 v = Tr[(size_t)s * 64 + lane];
        float f[8]; unpack8(v, f);
        #pragma unroll
        for (int j = 0; j < 8; ++j) acc[j] += w * f[j];
    }
    const float4 b0 = ((const float4*)bias)[lane*2];
    const float4 b1 = ((const float4*)bias)[lane*2 + 1];
    float r[8] = {acc[0]+b0.x, acc[1]+b0.y, acc[2]+b0.z, acc[3]+b0.w,
                  acc[4]+b1.x, acc[5]+b1.y, acc[6]+b1.z, acc[7]+b1.w};
    u32x4 o;
    o.x = f2bf_bits(fmaxf(r[0],0.f)) | (f2bf_bits(fmaxf(r[1],0.f)) << 16);
    o.y = f2bf_bits(fmaxf(r[2],0.f)) | (f2bf_bits(fmaxf(r[3],0.f)) << 16);
    o.z = f2bf_bits(fmaxf(r[4],0.f)) | (f2bf_bits(fmaxf(r[5],0.f)) << 16);
    o.w = f2bf_bits(fmaxf(r[6],0.f)) | (f2bf_bits(fmaxf(r[7],0.f)) << 16);
    __builtin_nontemporal_store(o, ((u32x4*)(H + (size_t)gw * 512)) + lane);
}

// layer 2: out[i] = sum_e norm*T[src] + dinv[i]^2*T[i] + b, D=256, fp32 out.
// TWO nodes per wave (proven layout), x4 unroll + serial remainder.
__global__ __launch_bounds__(256)
void agg_bias_out_256(const bf16_t* __restrict__ T, const int* __restrict__ rowp,
                      const int* __restrict__ csrc, const float* __restrict__ cnorm,
                      const float* __restrict__ dinv, const float* __restrict__ bias,
                      float* __restrict__ out)
{
    const int wid  = (blockIdx.x * 256 + threadIdx.x) >> 6;
    const int half = (threadIdx.x >> 5) & 1;
    const int l32  = threadIdx.x & 31;
    const int node = wid * 2 + half;
    if (node >= N_NODES) return;
    const float di = dinv[node];
    float acc[8];
    {
        uint4 v = ((const uint4*)(T + (size_t)node * 256))[l32];
        float f[8]; unpack8(v, f);
        const float w = di * di;
        #pragma unroll
        for (int j = 0; j < 8; ++j) acc[j] = w * f[j];
    }
    int e = rowp[node];
    const int e1 = rowp[node + 1];
    for (; e + 4 <= e1; e += 4){
        const int   s0 = csrc[e],   s1 = csrc[e+1], s2 = csrc[e+2], s3 = csrc[e+3];
        const float w0 = cnorm[e],  w1 = cnorm[e+1], w2 = cnorm[e+2], w3 = cnorm[e+3];
        uint4 v0 = ((const uint4*)(T + (size_t)s0 * 256))[l32];
        uint4 v1 = ((const uint4*)(T + (size_t)s1 * 256))[l32];
        uint4 v2 = ((const uint4*)(T + (size_t)s2 * 256))[l32];
        uint4 v3 = ((const uint4*)(T + (size_t)s3 * 256))[l32];
        float f[8];
        unpack8(v0, f);
        #pragma unroll
        for (int j = 0; j < 8; ++j) acc[j] += w0 * f[j];
        unpack8(v1, f);
        #pragma unroll
        for (int j = 0; j < 8; ++j) acc[j] += w1 * f[j];
        unpack8(v2, f);
        #pragma unroll
        for (int j = 0; j < 8; ++j) acc[j] += w2 * f[j];
        unpack8(v3, f);
        #pragma unroll
        for (int j = 0; j < 8; ++j) acc[j] += w3 * f[j];
    }
    for (; e < e1; ++e){
        const int   s = csrc[e];
        const float w = cnorm[e];
        uint4 v = ((const uint4*)(T + (size_t)s * 256))[l32];
        float f[8]; unpack8(v, f);
        #pragma unroll
        for (int j = 0; j < 8; ++j) acc[j] += w * f[j];
    }
    const float4 b0 = ((const float4*)bias)[l32*2];
    const float4 b1 = ((const float4*)bias)[l32*2 + 1];
    f32x4 o0 = {acc[0]+b0.x, acc[1]+b0.y, acc[2]+b0.z, acc[3]+b0.w};
    f32x4 o1 = {acc[4]+b1.x, acc[5]+b1.y, acc[6]+b1.z, acc[7]+b1.w};
    __builtin_nontemporal_store(o0, ((f32x4*)(out + (size_t)node * 256)) + l32*2);
    __builtin_nontemporal_store(o1, ((f32x4*)(out + (size_t)node * 256)) + l32*2 + 1);
}

// ---------- host ----------
extern "C" void kernel_launch(void* const* d_in, const int* in_sizes, int n_in,
                              void* d_out, int out_size, void* d_ws, size_t ws_size,
                              hipStream_t stream)
{
    const float* x  = (const float*)d_in[0];
    const int*   ei = (const int*)d_in[1];     // [0..4e5)=src, [4e5..8e5)=dst
    const float* W1 = (const float*)d_in[2];
    const float* b1 = (const float*)d_in[3];
    const float* W2 = (const float*)d_in[4];
    const float* b2 = (const float*)d_in[5];
    float* out = (float*)d_out;

    // workspace carve (256B aligned)
    char* w = (char*)d_ws;
    auto alloc = [&](size_t bytes) -> char* {
        char* p = w; w += (bytes + 255) & ~(size_t)255; return p;
    };
    bf16_t* Xb    = (bf16_t*)alloc((size_t)M_PAD * 512 * 2);  // Xb, later reused as H
    bf16_t* T     = (bf16_t*)alloc((size_t)M_PAD * 512 * 2);  // T1, later reused as T2
    bf16_t* W1t   = (bf16_t*)alloc(512 * 512 * 2);
    bf16_t* W2t   = (bf16_t*)alloc(256 * 512 * 2);
    int*    deg   = (int*)  alloc(N_NODES * 4);
    float*  dinv  = (float*)alloc(N_NODES * 4);
    int*    rowp  = (int*)  alloc((N_NODES + 1) * 4);
    int*    cursor= (int*)  alloc(N_NODES * 4);
    int*    part  = (int*)  alloc(N_NODES * 4);
    int*    bsum  = (int*)  alloc(NB_SCAN * 4);
    int*    bsum2 = (int*)  alloc(NB_SCAN * 4);
    int*    csrc  = (int*)  alloc(N_EDGES * 4);
    float*  cnorm = (float*)alloc(N_EDGES * 4);

    // dtype conversion + deg init
    conv_x_bf16<<<(M_PAD*128)/256, 256, 0, stream>>>(x, Xb, deg);
    // weight transposes + edge degree count
    conv_w_both<<<1568, 256, 0, stream>>>(W1, W2, W1t, W2t, ei, deg);

    // CSR build (scan chain — proven)
    k_scan_dinv<<<NB_SCAN, 256, 0, stream>>>(deg, dinv, part, bsum, N_NODES);
    k_scan_bsum <<<1, 256, 0, stream>>>(bsum, bsum2, NB_SCAN);
    k_finalize_rowptr<<<NB_SCAN, 256, 0, stream>>>(part, bsum2, rowp, cursor, N_NODES);
    k_place   <<<(N_EDGES+255)/256, 256, 0, stream>>>(ei, dinv, cursor, csrc, cnorm);

    // layer 1: T1 = Xb @ W1 ; H = relu(agg(T1) + b1)   (H reuses Xb buffer)
    gemm_bf16_mfma<<<dim3(M_PAD/128, 512/256), 256, 0, stream>>>(Xb, W1t, T, 512, 512);
    agg_bias_relu_512<<<(N_NODES+3)/4, 256, 0, stream>>>(T, rowp, csrc, cnorm, dinv, b1, Xb);

    // layer 2: T2 = H @ W2 ; out = agg(T2) + b2        (T2 reuses T buffer)
    gemm_bf16_mfma<<<dim3(M_PAD/128, 256/256), 256, 0, stream>>>(Xb, W2t, T, 256, 512);
    agg_bias_out_256<<<(25000+3)/4, 256, 0, stream>>>(T, rowp, csrc, cnorm, dinv, b2, out);
}